// Round 5
// baseline (1109.603 us; speedup 1.0000x reference)
//
#include <hip/hip_runtime.h>
#include <math.h>

#define Hh 192
#define Ww 192
#define HWc 36864
#define Bc 4
#define NWc 576
#define NKc 288
#define WNc 24

// ---- K1: q/k/v 1x1 convs (48 -> 3x64), output layout [b][y][x][c] ----
// lane = output channel: weights resident in VGPRs (no recurring scalar
// loads); x staged in LDS, read via conflict-free broadcast ds_read_b128;
// stores are 256B contiguous per wave instr (no transpose, no amplification).
__global__ __launch_bounds__(256, 2) void k_qkv(const float* __restrict__ x,
    const float* __restrict__ wq, const float* __restrict__ bq,
    const float* __restrict__ wk, const float* __restrict__ bk,
    const float* __restrict__ wvw, const float* __restrict__ bv,
    float* __restrict__ q, float* __restrict__ k, float* __restrict__ v)
{
    __shared__ float xs[256][52];      // 53248 B; stride 52 keeps b128 align

    int tid = threadIdx.x;
    int blk = blockIdx.x;
    int b = blk / 144;
    int g0 = (blk % 144) * 256;        // block's pixel base within image
    const float* xb = x + (size_t)b * 48 * HWc + g0;

    // stage x: thread tid owns pixel tid; 48 coalesced 256B wave-loads
    #pragma unroll 8
    for (int c = 0; c < 48; ++c) xs[tid][c] = xb[(size_t)c * HWc + tid];

    // per-lane weights: lane = output channel
    int ln = tid & 63, wave = tid >> 6;
    float wqr[48], wkr[48], wvr[48];
    #pragma unroll
    for (int j = 0; j < 12; ++j) {
        float4 a4 = *(const float4*)(wq + ln * 48 + j * 4);
        wqr[j*4+0] = a4.x; wqr[j*4+1] = a4.y; wqr[j*4+2] = a4.z; wqr[j*4+3] = a4.w;
        float4 b4 = *(const float4*)(wk + ln * 48 + j * 4);
        wkr[j*4+0] = b4.x; wkr[j*4+1] = b4.y; wkr[j*4+2] = b4.z; wkr[j*4+3] = b4.w;
        float4 c4 = *(const float4*)(wvw + ln * 48 + j * 4);
        wvr[j*4+0] = c4.x; wvr[j*4+1] = c4.y; wvr[j*4+2] = c4.z; wvr[j*4+3] = c4.w;
    }
    float bqv = bq[ln], bkv = bk[ln], bvv = bv[ln];
    __syncthreads();

    size_t obase = ((size_t)b * HWc + g0) * 64 + ln;
    #pragma unroll 1
    for (int i = 0; i < 64; ++i) {
        int px = wave * 64 + i;
        float xr[48];
        #pragma unroll
        for (int j = 0; j < 12; ++j) {
            float4 x4 = *(const float4*)&xs[px][j * 4];   // broadcast read
            xr[j*4+0] = x4.x; xr[j*4+1] = x4.y; xr[j*4+2] = x4.z; xr[j*4+3] = x4.w;
        }
        float aq = bqv, ak = bkv, av = bvv;
        #pragma unroll
        for (int c = 0; c < 48; ++c) {
            aq = fmaf(xr[c], wqr[c], aq);
            ak = fmaf(xr[c], wkr[c], ak);
            av = fmaf(xr[c], wvr[c], av);
        }
        q[obase + (size_t)px * 64] = aq;
        k[obase + (size_t)px * 64] = ak;
        v[obase + (size_t)px * 64] = av;
    }
}

// ------- K2: cond conv (68->17) + LayerNorm + leaky + channel-mean -------
__global__ __launch_bounds__(256) void k_cond(const float* __restrict__ vs,
    const float* __restrict__ cg,
    const float* __restrict__ w_in, const float* __restrict__ b_in,
    const float* __restrict__ ln_w, const float* __restrict__ ln_b,
    float* __restrict__ t, float* __restrict__ mpix)
{
    int g = blockIdx.x * 256 + threadIdx.x;
    int b = g / HWc, rem = g % HWc;
    int y = rem / Ww, xx = rem % Ww;

    float in[68];
    const float* vp = vs + (size_t)g * 64;
    #pragma unroll
    for (int c = 0; c < 64; c += 4) {
        float4 t4 = *(const float4*)(vp + c);
        in[c] = t4.x; in[c+1] = t4.y; in[c+2] = t4.z; in[c+3] = t4.w;
    }
    in[64] = cg[((size_t)b * 2 + 0) * HWc + rem];
    in[65] = cg[((size_t)b * 2 + 1) * HWc + rem];
    const float step = 2.0f / 7.0f;
    in[66] = -1.0f + step * (float)(y & 7);
    in[67] = -1.0f + step * (float)(xx & 7);

    float tv[17];
    float mu = 0.f;
    #pragma unroll
    for (int o = 0; o < 17; ++o) {
        float a = b_in[o];
        const float* wr = w_in + o * 68;
        #pragma unroll
        for (int c = 0; c < 68; ++c) a = fmaf(in[c], wr[c], a);
        tv[o] = a;
        mu += a;
    }
    mu *= (1.f / 17.f);
    float var = 0.f;
    #pragma unroll
    for (int o = 0; o < 17; ++o) { float d = tv[o] - mu; var = fmaf(d, d, var); }
    var *= (1.f / 17.f);
    float rstd = 1.f / sqrtf(var + 1e-6f);

    float msum = 0.f;
    #pragma unroll
    for (int o = 0; o < 17; ++o) {
        float z = (tv[o] - mu) * rstd * ln_w[o] + ln_b[o];
        z = (z >= 0.f) ? z : 0.1f * z;
        t[((size_t)b * 17 + o) * HWc + rem] = z;
        msum += z;
    }
    mpix[(size_t)b * HWc + rem] = msum * (1.f / 17.f);
}

// ---------------- K3: 3x3 conv (17->1) + sigmoid ----------------
__global__ __launch_bounds__(256) void k_sa(const float* __restrict__ t,
    const float* __restrict__ w_sa, const float* __restrict__ b_sa,
    float* __restrict__ sa)
{
    int g = blockIdx.x * 256 + threadIdx.x;
    int b = g / HWc, rem = g % HWc;
    int y = rem / Ww, xx = rem % Ww;

    float a = b_sa[0];
    for (int c = 0; c < 17; ++c) {
        const float* tp = t + ((size_t)b * 17 + c) * HWc;
        const float* wr = w_sa + c * 9;
        #pragma unroll
        for (int ki = 0; ki < 3; ++ki) {
            int yy = y + ki - 1;
            if ((unsigned)yy >= 192u) continue;
            #pragma unroll
            for (int kj = 0; kj < 3; ++kj) {
                int xc = xx + kj - 1;
                if ((unsigned)xc >= 192u) continue;
                a = fmaf(tp[yy * Ww + xc], wr[ki * 3 + kj], a);
            }
        }
    }
    sa[g] = 1.f / (1.f + expf(-a));
}

// -------- K4: window score MLP + stable descending rank -> flag --------
__global__ __launch_bounds__(576) void k_score(const float* __restrict__ mpix,
    const float* __restrict__ w_m1, const float* __restrict__ b_m1,
    const float* __restrict__ w_m2, const float* __restrict__ b_m2,
    int* __restrict__ flag)
{
    __shared__ float sc[NWc];
    int b = blockIdx.x;
    int w = threadIdx.x;
    {
        int hy = w / WNc, wx = w % WNc;
        const float* mp = mpix + (size_t)b * HWc + (hy * 8) * Ww + wx * 8;
        float m[64];
        #pragma unroll
        for (int l = 0; l < 64; ++l) m[l] = mp[(l >> 3) * Ww + (l & 7)];
        float h1[8];
        #pragma unroll
        for (int j = 0; j < 8; ++j) {
            float a = b_m1[j];
            const float* wr = w_m1 + j * 64;
            #pragma unroll
            for (int l = 0; l < 64; ++l) a = fmaf(m[l], wr[l], a);
            h1[j] = (a >= 0.f) ? a : 0.1f * a;
        }
        float l0 = b_m2[0], l1 = b_m2[1];
        #pragma unroll
        for (int j = 0; j < 8; ++j) {
            l0 = fmaf(h1[j], w_m2[j], l0);
            l1 = fmaf(h1[j], w_m2[8 + j], l1);
        }
        float mx = fmaxf(l0, l1);
        float e0 = expf(l0 - mx), e1 = expf(l1 - mx);
        sc[w] = e0 / (e0 + e1);
    }
    __syncthreads();
    float s = sc[w];
    int cnt = 0;
    for (int w2 = 0; w2 < NWc; ++w2) {
        float s2 = sc[w2];
        cnt += ((s2 > s) || (s2 == s && w2 < w)) ? 1 : 0;
    }
    flag[b * NWc + w] = (cnt < NKc) ? 1 : 0;
}

// ---- K5: per-window attention (LDS-staged K/V) + fused output conv ----
__global__ __launch_bounds__(256) void k_attn(const float* __restrict__ qs,
    const float* __restrict__ ks, const float* __restrict__ vsb,
    const float* __restrict__ sab, const int* __restrict__ flag,
    const float* __restrict__ relh, const float* __restrict__ relw,
    const float* __restrict__ w_out, const float* __restrict__ b_out,
    float* __restrict__ out)
{
    __shared__ float kbuf[144 * 64];   // 36864 B; aliased as mlds[64][65] later
    __shared__ float vbuf[144 * 64];   // 36864 B
    float (*mlds)[65] = (float (*)[65])kbuf;

    int tid = threadIdx.x;
    int blk = blockIdx.x;
    int b = blk / NWc, n = blk % NWc;
    int hy = n / WNc, wx = n % WNc;
    int y0 = hy * 8, x0 = wx * 8;

    if (flag[b * NWc + n]) {
        // ---- cooperative stage of 12x12x64 K and V patches, zero-filled OOB ----
        #pragma unroll
        for (int i = 0; i < 9; ++i) {
            int idx = i * 256 + tid;          // 0..2303 = 144 px * 16 chunks
            int px = idx >> 4, c4 = idx & 15;
            int py = px / 12, pxx = px - py * 12;
            int ky = y0 - 2 + py, kx = x0 - 2 + pxx;
            bool ok = ((unsigned)ky < 192u) && ((unsigned)kx < 192u);
            int kyc = min(max(ky, 0), 191), kxc = min(max(kx, 0), 191);
            size_t goff = ((size_t)(b * HWc) + kyc * Ww + kxc) * 64 + c4 * 4;
            float4 k4 = *(const float4*)(ks + goff);
            float4 v4 = *(const float4*)(vsb + goff);
            if (!ok) { k4 = make_float4(0,0,0,0); v4 = make_float4(0,0,0,0); }
            *(float4*)(kbuf + px * 64 + c4 * 4) = k4;
            *(float4*)(vbuf + px * 64 + c4 * 4) = v4;
        }
        __syncthreads();

        int h = __builtin_amdgcn_readfirstlane(tid >> 6);  // head, SGPR
        int l = tid & 63;
        int qr = l >> 3, qc = l & 7;

        const float* qp = qs + ((size_t)(b * HWc) + (y0 + qr) * Ww + (x0 + qc)) * 64 + h * 16;
        float qv[16];
        #pragma unroll
        for (int j = 0; j < 4; ++j) {
            float4 t4 = *(const float4*)(qp + j * 4);
            qv[j*4+0] = t4.x; qv[j*4+1] = t4.y; qv[j*4+2] = t4.z; qv[j*4+3] = t4.w;
        }

        // relative-position logit tables (rel index in [4,22], always valid)
        float rw[12], rh[12];
        #pragma unroll
        for (int kc = 0; kc < 12; ++kc) {
            const float* rp = relw + (kc - qc + 11) * 16;
            float a = 0.f;
            #pragma unroll
            for (int j = 0; j < 4; ++j) {
                float4 t4 = *(const float4*)(rp + j * 4);
                a = fmaf(qv[j*4+0], t4.x, a); a = fmaf(qv[j*4+1], t4.y, a);
                a = fmaf(qv[j*4+2], t4.z, a); a = fmaf(qv[j*4+3], t4.w, a);
            }
            rw[kc] = a;
        }
        #pragma unroll
        for (int kr = 0; kr < 12; ++kr) {
            const float* rp = relh + (kr - qr + 11) * 16;
            float a = 0.f;
            #pragma unroll
            for (int j = 0; j < 4; ++j) {
                float4 t4 = *(const float4*)(rp + j * 4);
                a = fmaf(qv[j*4+0], t4.x, a); a = fmaf(qv[j*4+1], t4.y, a);
                a = fmaf(qv[j*4+2], t4.z, a); a = fmaf(qv[j*4+3], t4.w, a);
            }
            rh[kr] = a;
        }

        // cheap shift (upper bound of rel part) -> exp arg bounded, softmax invariant
        float mw = rw[0], mh = rh[0];
        #pragma unroll
        for (int i = 1; i < 12; ++i) { mw = fmaxf(mw, rw[i]); mh = fmaxf(mh, rh[i]); }
        float mrel = mw + mh;

        float lsum = 0.f;
        float acc[16];
        #pragma unroll
        for (int d = 0; d < 16; ++d) acc[d] = 0.f;

        // ---- branchless 144-key loop, K/V from LDS (broadcast reads) ----
        #pragma unroll 1
        for (int kr = 0; kr < 12; ++kr) {
            float rhv = rh[kr];
            const float* kRow = kbuf + (kr * 12) * 64 + h * 16;
            const float* vRow = vbuf + (kr * 12) * 64 + h * 16;
            #pragma unroll 4
            for (int kc = 0; kc < 12; ++kc) {
                const float* kp = kRow + kc * 64;
                float dt = 0.f;
                #pragma unroll
                for (int j = 0; j < 4; ++j) {
                    float4 k4 = *(const float4*)(kp + j * 4);
                    dt = fmaf(qv[j*4+0], k4.x, dt); dt = fmaf(qv[j*4+1], k4.y, dt);
                    dt = fmaf(qv[j*4+2], k4.z, dt); dt = fmaf(qv[j*4+3], k4.w, dt);
                }
                float s = rw[kc] + rhv - mrel + 0.25f * dt;
                float e = __expf(s);
                lsum += e;
                const float* vp2 = vRow + kc * 64;
                #pragma unroll
                for (int j = 0; j < 4; ++j) {
                    float4 v4 = *(const float4*)(vp2 + j * 4);
                    acc[j*4+0] = fmaf(e, v4.x, acc[j*4+0]);
                    acc[j*4+1] = fmaf(e, v4.y, acc[j*4+1]);
                    acc[j*4+2] = fmaf(e, v4.z, acc[j*4+2]);
                    acc[j*4+3] = fmaf(e, v4.w, acc[j*4+3]);
                }
            }
        }
        __syncthreads();   // everyone done reading kbuf before aliased mlds write
        float inv = 1.f / lsum;
        #pragma unroll
        for (int d = 0; d < 16; ++d) mlds[l][h * 16 + d] = acc[d] * inv;
    } else {
        // easy path: vs * sa
        int l = tid >> 2, part = tid & 3;
        int gy = y0 + (l >> 3), gx = x0 + (l & 7);
        const float* vp = vsb + ((size_t)(b * HWc) + gy * Ww + gx) * 64 + part * 16;
        float sv = sab[(size_t)b * HWc + gy * Ww + gx];
        #pragma unroll
        for (int j = 0; j < 4; ++j) {
            float4 v4 = *(const float4*)(vp + j * 4);
            mlds[l][part*16 + j*4 + 0] = v4.x * sv;
            mlds[l][part*16 + j*4 + 1] = v4.y * sv;
            mlds[l][part*16 + j*4 + 2] = v4.z * sv;
            mlds[l][part*16 + j*4 + 3] = v4.w * sv;
        }
    }
    __syncthreads();

    // fused output conv: 64 -> 48 per pixel (weights via wave-uniform s_loads)
    {
        int l = tid & 63;
        int og = __builtin_amdgcn_readfirstlane(tid >> 6);
        int gy = y0 + (l >> 3), gx = x0 + (l & 7);
        float mv[64];
        #pragma unroll
        for (int c = 0; c < 64; ++c) mv[c] = mlds[l][c];
        #pragma unroll 1
        for (int j = 0; j < 12; ++j) {
            int oc = og * 12 + j;
            float a = b_out[oc];
            const float* wr = w_out + oc * 64;
            #pragma unroll
            for (int c = 0; c < 64; ++c) a = fmaf(mv[c], wr[c], a);
            out[((size_t)(b * 48 + oc)) * HWc + gy * Ww + gx] = a;
        }
    }
}

extern "C" void kernel_launch(void* const* d_in, const int* in_sizes, int n_in,
                              void* d_out, int out_size, void* d_ws, size_t ws_size,
                              hipStream_t stream)
{
    const float* x    = (const float*)d_in[0];
    const float* cg   = (const float*)d_in[1];
    const float* wq   = (const float*)d_in[2];
    const float* bq   = (const float*)d_in[3];
    const float* wk   = (const float*)d_in[4];
    const float* bk   = (const float*)d_in[5];
    const float* wv   = (const float*)d_in[6];
    const float* bv   = (const float*)d_in[7];
    const float* w_in = (const float*)d_in[8];
    const float* b_in = (const float*)d_in[9];
    const float* ln_w = (const float*)d_in[10];
    const float* ln_b = (const float*)d_in[11];
    const float* w_sa = (const float*)d_in[12];
    const float* b_sa = (const float*)d_in[13];
    const float* w_m1 = (const float*)d_in[14];
    const float* b_m1 = (const float*)d_in[15];
    const float* w_m2 = (const float*)d_in[16];
    const float* b_m2 = (const float*)d_in[17];
    const float* rel_h= (const float*)d_in[18];
    const float* rel_w= (const float*)d_in[19];
    const float* w_out= (const float*)d_in[20];
    const float* b_out= (const float*)d_in[21];
    float* out = (float*)d_out;

    float* ws   = (float*)d_ws;
    float* qs   = ws;
    float* ks   = qs + (size_t)Bc * 64 * HWc;
    float* vs   = ks + (size_t)Bc * 64 * HWc;
    float* t    = vs + (size_t)Bc * 64 * HWc;
    float* sa   = t  + (size_t)Bc * 17 * HWc;
    float* mpix = sa + (size_t)Bc * HWc;
    int*   flag = (int*)(mpix + (size_t)Bc * HWc);

    k_qkv  <<<576, 256, 0, stream>>>(x, wq, bq, wk, bk, wv, bv, qs, ks, vs);
    k_cond <<<576, 256, 0, stream>>>(vs, cg, w_in, b_in, ln_w, ln_b, t, mpix);
    k_sa   <<<576, 256, 0, stream>>>(t, w_sa, b_sa, sa);
    k_score<<<4, 576, 0, stream>>>(mpix, w_m1, b_m1, w_m2, b_m2, flag);
    k_attn <<<2304, 256, 0, stream>>>(qs, ks, vs, sa, flag, rel_h, rel_w, w_out, b_out, out);
}

// Round 6
// 318.361 us; speedup vs baseline: 3.4854x; 3.4854x over previous
//
#include <hip/hip_runtime.h>
#include <math.h>

#define Hh 192
#define Ww 192
#define HWc 36864
#define Bc 4
#define NWc 576
#define NKc 288
#define WNc 24

// ---- K1: q/k/v 1x1 convs (48 -> 3x64), output layout [b][y][x][c] ----
// lane = output channel; weights live in 144 VGPRs (36 float4, compile-time
// indexed); x staged in LDS and consumed chunk-by-chunk (no xr[] array ->
// live set ~165 regs, under the 256 cap; launch_bounds(256,1) lifts the
// allocator's occupancy target so it must not spill).
__global__ __launch_bounds__(256, 1) void k_qkv(const float* __restrict__ x,
    const float* __restrict__ wq, const float* __restrict__ bq,
    const float* __restrict__ wk, const float* __restrict__ bk,
    const float* __restrict__ wvw, const float* __restrict__ bv,
    float* __restrict__ q, float* __restrict__ k, float* __restrict__ v)
{
    __shared__ float xs[256][52];      // 53248 B; 208B row stride (16B aligned)

    int tid = threadIdx.x;
    int blk = blockIdx.x;
    int b = blk / 144;
    int g0 = (blk % 144) * 256;        // block's pixel base within image
    const float* xb = x + (size_t)b * 48 * HWc + g0;

    // stage x: thread tid owns pixel tid; 48 coalesced 256B wave-loads
    #pragma unroll 8
    for (int c = 0; c < 48; ++c) xs[tid][c] = xb[(size_t)c * HWc + tid];

    // per-lane weights: lane = output channel (fully unrolled, static idx)
    int ln = tid & 63, wave = tid >> 6;
    float4 Wq[12], Wk[12], Wv[12];
    #pragma unroll
    for (int j = 0; j < 12; ++j) {
        Wq[j] = *(const float4*)(wq  + ln * 48 + j * 4);
        Wk[j] = *(const float4*)(wk  + ln * 48 + j * 4);
        Wv[j] = *(const float4*)(wvw + ln * 48 + j * 4);
    }
    float bqv = bq[ln], bkv = bk[ln], bvv = bv[ln];
    __syncthreads();

    size_t obase = ((size_t)b * HWc + g0) * 64 + ln;
    #pragma unroll 1
    for (int i = 0; i < 64; ++i) {
        int px = wave * 64 + i;
        float aq = bqv, ak = bkv, av = bvv;
        #pragma unroll
        for (int j = 0; j < 12; ++j) {
            float4 x4 = *(const float4*)&xs[px][j * 4];   // broadcast ds_read_b128
            aq = fmaf(x4.x, Wq[j].x, aq); ak = fmaf(x4.x, Wk[j].x, ak); av = fmaf(x4.x, Wv[j].x, av);
            aq = fmaf(x4.y, Wq[j].y, aq); ak = fmaf(x4.y, Wk[j].y, ak); av = fmaf(x4.y, Wv[j].y, av);
            aq = fmaf(x4.z, Wq[j].z, aq); ak = fmaf(x4.z, Wk[j].z, ak); av = fmaf(x4.z, Wv[j].z, av);
            aq = fmaf(x4.w, Wq[j].w, aq); ak = fmaf(x4.w, Wk[j].w, ak); av = fmaf(x4.w, Wv[j].w, av);
        }
        q[obase + (size_t)px * 64] = aq;
        k[obase + (size_t)px * 64] = ak;
        v[obase + (size_t)px * 64] = av;
    }
}

// ------- K2: cond conv (68->17) + LayerNorm + leaky + channel-mean -------
__global__ __launch_bounds__(256) void k_cond(const float* __restrict__ vs,
    const float* __restrict__ cg,
    const float* __restrict__ w_in, const float* __restrict__ b_in,
    const float* __restrict__ ln_w, const float* __restrict__ ln_b,
    float* __restrict__ t, float* __restrict__ mpix)
{
    int g = blockIdx.x * 256 + threadIdx.x;
    int b = g / HWc, rem = g % HWc;
    int y = rem / Ww, xx = rem % Ww;

    float in[68];
    const float* vp = vs + (size_t)g * 64;
    #pragma unroll
    for (int c = 0; c < 64; c += 4) {
        float4 t4 = *(const float4*)(vp + c);
        in[c] = t4.x; in[c+1] = t4.y; in[c+2] = t4.z; in[c+3] = t4.w;
    }
    in[64] = cg[((size_t)b * 2 + 0) * HWc + rem];
    in[65] = cg[((size_t)b * 2 + 1) * HWc + rem];
    const float step = 2.0f / 7.0f;
    in[66] = -1.0f + step * (float)(y & 7);
    in[67] = -1.0f + step * (float)(xx & 7);

    float tv[17];
    float mu = 0.f;
    #pragma unroll
    for (int o = 0; o < 17; ++o) {
        float a = b_in[o];
        const float* wr = w_in + o * 68;
        #pragma unroll
        for (int c = 0; c < 68; ++c) a = fmaf(in[c], wr[c], a);
        tv[o] = a;
        mu += a;
    }
    mu *= (1.f / 17.f);
    float var = 0.f;
    #pragma unroll
    for (int o = 0; o < 17; ++o) { float d = tv[o] - mu; var = fmaf(d, d, var); }
    var *= (1.f / 17.f);
    float rstd = 1.f / sqrtf(var + 1e-6f);

    float msum = 0.f;
    #pragma unroll
    for (int o = 0; o < 17; ++o) {
        float z = (tv[o] - mu) * rstd * ln_w[o] + ln_b[o];
        z = (z >= 0.f) ? z : 0.1f * z;
        t[((size_t)b * 17 + o) * HWc + rem] = z;
        msum += z;
    }
    mpix[(size_t)b * HWc + rem] = msum * (1.f / 17.f);
}

// ---------------- K3: 3x3 conv (17->1) + sigmoid ----------------
__global__ __launch_bounds__(256) void k_sa(const float* __restrict__ t,
    const float* __restrict__ w_sa, const float* __restrict__ b_sa,
    float* __restrict__ sa)
{
    int g = blockIdx.x * 256 + threadIdx.x;
    int b = g / HWc, rem = g % HWc;
    int y = rem / Ww, xx = rem % Ww;

    float a = b_sa[0];
    for (int c = 0; c < 17; ++c) {
        const float* tp = t + ((size_t)b * 17 + c) * HWc;
        const float* wr = w_sa + c * 9;
        #pragma unroll
        for (int ki = 0; ki < 3; ++ki) {
            int yy = y + ki - 1;
            if ((unsigned)yy >= 192u) continue;
            #pragma unroll
            for (int kj = 0; kj < 3; ++kj) {
                int xc = xx + kj - 1;
                if ((unsigned)xc >= 192u) continue;
                a = fmaf(tp[yy * Ww + xc], wr[ki * 3 + kj], a);
            }
        }
    }
    sa[g] = 1.f / (1.f + expf(-a));
}

// -------- K4: window score MLP + stable descending rank -> flag --------
__global__ __launch_bounds__(576) void k_score(const float* __restrict__ mpix,
    const float* __restrict__ w_m1, const float* __restrict__ b_m1,
    const float* __restrict__ w_m2, const float* __restrict__ b_m2,
    int* __restrict__ flag)
{
    __shared__ float sc[NWc];
    int b = blockIdx.x;
    int w = threadIdx.x;
    {
        int hy = w / WNc, wx = w % WNc;
        const float* mp = mpix + (size_t)b * HWc + (hy * 8) * Ww + wx * 8;
        float m[64];
        #pragma unroll
        for (int l = 0; l < 64; ++l) m[l] = mp[(l >> 3) * Ww + (l & 7)];
        float h1[8];
        #pragma unroll
        for (int j = 0; j < 8; ++j) {
            float a = b_m1[j];
            const float* wr = w_m1 + j * 64;
            #pragma unroll
            for (int l = 0; l < 64; ++l) a = fmaf(m[l], wr[l], a);
            h1[j] = (a >= 0.f) ? a : 0.1f * a;
        }
        float l0 = b_m2[0], l1 = b_m2[1];
        #pragma unroll
        for (int j = 0; j < 8; ++j) {
            l0 = fmaf(h1[j], w_m2[j], l0);
            l1 = fmaf(h1[j], w_m2[8 + j], l1);
        }
        float mx = fmaxf(l0, l1);
        float e0 = expf(l0 - mx), e1 = expf(l1 - mx);
        sc[w] = e0 / (e0 + e1);
    }
    __syncthreads();
    float s = sc[w];
    int cnt = 0;
    for (int w2 = 0; w2 < NWc; ++w2) {
        float s2 = sc[w2];
        cnt += ((s2 > s) || (s2 == s && w2 < w)) ? 1 : 0;
    }
    flag[b * NWc + w] = (cnt < NKc) ? 1 : 0;
}

// ---- K5: per-window attention (LDS-staged K/V) + fused output conv ----
__global__ __launch_bounds__(256) void k_attn(const float* __restrict__ qs,
    const float* __restrict__ ks, const float* __restrict__ vsb,
    const float* __restrict__ sab, const int* __restrict__ flag,
    const float* __restrict__ relh, const float* __restrict__ relw,
    const float* __restrict__ w_out, const float* __restrict__ b_out,
    float* __restrict__ out)
{
    __shared__ float kbuf[144 * 64];   // 36864 B; aliased as mlds[64][65] later
    __shared__ float vbuf[144 * 64];   // 36864 B
    float (*mlds)[65] = (float (*)[65])kbuf;

    int tid = threadIdx.x;
    int blk = blockIdx.x;
    int b = blk / NWc, n = blk % NWc;
    int hy = n / WNc, wx = n % WNc;
    int y0 = hy * 8, x0 = wx * 8;

    if (flag[b * NWc + n]) {
        // ---- cooperative stage of 12x12x64 K and V patches, zero-filled OOB ----
        #pragma unroll
        for (int i = 0; i < 9; ++i) {
            int idx = i * 256 + tid;          // 0..2303 = 144 px * 16 chunks
            int px = idx >> 4, c4 = idx & 15;
            int py = px / 12, pxx = px - py * 12;
            int ky = y0 - 2 + py, kx = x0 - 2 + pxx;
            bool ok = ((unsigned)ky < 192u) && ((unsigned)kx < 192u);
            int kyc = min(max(ky, 0), 191), kxc = min(max(kx, 0), 191);
            size_t goff = ((size_t)(b * HWc) + kyc * Ww + kxc) * 64 + c4 * 4;
            float4 k4 = *(const float4*)(ks + goff);
            float4 v4 = *(const float4*)(vsb + goff);
            if (!ok) { k4 = make_float4(0,0,0,0); v4 = make_float4(0,0,0,0); }
            *(float4*)(kbuf + px * 64 + c4 * 4) = k4;
            *(float4*)(vbuf + px * 64 + c4 * 4) = v4;
        }
        __syncthreads();

        int h = __builtin_amdgcn_readfirstlane(tid >> 6);  // head, SGPR
        int l = tid & 63;
        int qr = l >> 3, qc = l & 7;

        const float* qp = qs + ((size_t)(b * HWc) + (y0 + qr) * Ww + (x0 + qc)) * 64 + h * 16;
        float qv[16];
        #pragma unroll
        for (int j = 0; j < 4; ++j) {
            float4 t4 = *(const float4*)(qp + j * 4);
            qv[j*4+0] = t4.x; qv[j*4+1] = t4.y; qv[j*4+2] = t4.z; qv[j*4+3] = t4.w;
        }

        // relative-position logit tables (rel index in [4,22], always valid)
        float rw[12], rh[12];
        #pragma unroll
        for (int kc = 0; kc < 12; ++kc) {
            const float* rp = relw + (kc - qc + 11) * 16;
            float a = 0.f;
            #pragma unroll
            for (int j = 0; j < 4; ++j) {
                float4 t4 = *(const float4*)(rp + j * 4);
                a = fmaf(qv[j*4+0], t4.x, a); a = fmaf(qv[j*4+1], t4.y, a);
                a = fmaf(qv[j*4+2], t4.z, a); a = fmaf(qv[j*4+3], t4.w, a);
            }
            rw[kc] = a;
        }
        #pragma unroll
        for (int kr = 0; kr < 12; ++kr) {
            const float* rp = relh + (kr - qr + 11) * 16;
            float a = 0.f;
            #pragma unroll
            for (int j = 0; j < 4; ++j) {
                float4 t4 = *(const float4*)(rp + j * 4);
                a = fmaf(qv[j*4+0], t4.x, a); a = fmaf(qv[j*4+1], t4.y, a);
                a = fmaf(qv[j*4+2], t4.z, a); a = fmaf(qv[j*4+3], t4.w, a);
            }
            rh[kr] = a;
        }

        // cheap shift (upper bound of rel part) -> exp arg bounded, softmax invariant
        float mw = rw[0], mh = rh[0];
        #pragma unroll
        for (int i = 1; i < 12; ++i) { mw = fmaxf(mw, rw[i]); mh = fmaxf(mh, rh[i]); }
        float mrel = mw + mh;

        float lsum = 0.f;
        float acc[16];
        #pragma unroll
        for (int d = 0; d < 16; ++d) acc[d] = 0.f;

        // ---- branchless 144-key loop, K/V from LDS (broadcast reads) ----
        #pragma unroll 1
        for (int kr = 0; kr < 12; ++kr) {
            float rhv = rh[kr];
            const float* kRow = kbuf + (kr * 12) * 64 + h * 16;
            const float* vRow = vbuf + (kr * 12) * 64 + h * 16;
            #pragma unroll 4
            for (int kc = 0; kc < 12; ++kc) {
                const float* kp = kRow + kc * 64;
                float dt = 0.f;
                #pragma unroll
                for (int j = 0; j < 4; ++j) {
                    float4 k4 = *(const float4*)(kp + j * 4);
                    dt = fmaf(qv[j*4+0], k4.x, dt); dt = fmaf(qv[j*4+1], k4.y, dt);
                    dt = fmaf(qv[j*4+2], k4.z, dt); dt = fmaf(qv[j*4+3], k4.w, dt);
                }
                float s = rw[kc] + rhv - mrel + 0.25f * dt;
                float e = __expf(s);
                lsum += e;
                const float* vp2 = vRow + kc * 64;
                #pragma unroll
                for (int j = 0; j < 4; ++j) {
                    float4 v4 = *(const float4*)(vp2 + j * 4);
                    acc[j*4+0] = fmaf(e, v4.x, acc[j*4+0]);
                    acc[j*4+1] = fmaf(e, v4.y, acc[j*4+1]);
                    acc[j*4+2] = fmaf(e, v4.z, acc[j*4+2]);
                    acc[j*4+3] = fmaf(e, v4.w, acc[j*4+3]);
                }
            }
        }
        __syncthreads();   // everyone done reading kbuf before aliased mlds write
        float inv = 1.f / lsum;
        #pragma unroll
        for (int d = 0; d < 16; ++d) mlds[l][h * 16 + d] = acc[d] * inv;
    } else {
        // easy path: vs * sa
        int l = tid >> 2, part = tid & 3;
        int gy = y0 + (l >> 3), gx = x0 + (l & 7);
        const float* vp = vsb + ((size_t)(b * HWc) + gy * Ww + gx) * 64 + part * 16;
        float sv = sab[(size_t)b * HWc + gy * Ww + gx];
        #pragma unroll
        for (int j = 0; j < 4; ++j) {
            float4 v4 = *(const float4*)(vp + j * 4);
            mlds[l][part*16 + j*4 + 0] = v4.x * sv;
            mlds[l][part*16 + j*4 + 1] = v4.y * sv;
            mlds[l][part*16 + j*4 + 2] = v4.z * sv;
            mlds[l][part*16 + j*4 + 3] = v4.w * sv;
        }
    }
    __syncthreads();

    // fused output conv: 64 -> 48 per pixel (weights via wave-uniform s_loads)
    {
        int l = tid & 63;
        int og = __builtin_amdgcn_readfirstlane(tid >> 6);
        int gy = y0 + (l >> 3), gx = x0 + (l & 7);
        float mv[64];
        #pragma unroll
        for (int c = 0; c < 64; ++c) mv[c] = mlds[l][c];
        #pragma unroll 1
        for (int j = 0; j < 12; ++j) {
            int oc = og * 12 + j;
            float a = b_out[oc];
            const float* wr = w_out + oc * 64;
            #pragma unroll
            for (int c = 0; c < 64; ++c) a = fmaf(mv[c], wr[c], a);
            out[((size_t)(b * 48 + oc)) * HWc + gy * Ww + gx] = a;
        }
    }
}

extern "C" void kernel_launch(void* const* d_in, const int* in_sizes, int n_in,
                              void* d_out, int out_size, void* d_ws, size_t ws_size,
                              hipStream_t stream)
{
    const float* x    = (const float*)d_in[0];
    const float* cg   = (const float*)d_in[1];
    const float* wq   = (const float*)d_in[2];
    const float* bq   = (const float*)d_in[3];
    const float* wk   = (const float*)d_in[4];
    const float* bk   = (const float*)d_in[5];
    const float* wv   = (const float*)d_in[6];
    const float* bv   = (const float*)d_in[7];
    const float* w_in = (const float*)d_in[8];
    const float* b_in = (const float*)d_in[9];
    const float* ln_w = (const float*)d_in[10];
    const float* ln_b = (const float*)d_in[11];
    const float* w_sa = (const float*)d_in[12];
    const float* b_sa = (const float*)d_in[13];
    const float* w_m1 = (const float*)d_in[14];
    const float* b_m1 = (const float*)d_in[15];
    const float* w_m2 = (const float*)d_in[16];
    const float* b_m2 = (const float*)d_in[17];
    const float* rel_h= (const float*)d_in[18];
    const float* rel_w= (const float*)d_in[19];
    const float* w_out= (const float*)d_in[20];
    const float* b_out= (const float*)d_in[21];
    float* out = (float*)d_out;

    float* ws   = (float*)d_ws;
    float* qs   = ws;
    float* ks   = qs + (size_t)Bc * 64 * HWc;
    float* vs   = ks + (size_t)Bc * 64 * HWc;
    float* t    = vs + (size_t)Bc * 64 * HWc;
    float* sa   = t  + (size_t)Bc * 17 * HWc;
    float* mpix = sa + (size_t)Bc * HWc;
    int*   flag = (int*)(mpix + (size_t)Bc * HWc);

    k_qkv  <<<576, 256, 0, stream>>>(x, wq, bq, wk, bk, wv, bv, qs, ks, vs);
    k_cond <<<576, 256, 0, stream>>>(vs, cg, w_in, b_in, ln_w, ln_b, t, mpix);
    k_sa   <<<576, 256, 0, stream>>>(t, w_sa, b_sa, sa);
    k_score<<<4, 576, 0, stream>>>(mpix, w_m1, b_m1, w_m2, b_m2, flag);
    k_attn <<<2304, 256, 0, stream>>>(qs, ks, vs, sa, flag, rel_h, rel_w, w_out, b_out, out);
}

// Round 8
// 293.339 us; speedup vs baseline: 3.7827x; 1.0853x over previous
//
#include <hip/hip_runtime.h>
#include <math.h>

#define Hh 192
#define Ww 192
#define HWc 36864
#define Bc 4
#define NWc 576
#define NKc 288
#define WNc 24

typedef _Float16 h2_t __attribute__((ext_vector_type(2)));
__device__ __forceinline__ h2_t u2h(unsigned u) { return __builtin_bit_cast(h2_t, u); }
__device__ __forceinline__ unsigned h2u(h2_t h) { return __builtin_bit_cast(unsigned, h); }
__device__ __forceinline__ h2_t pkrtz(float a, float b) {
    return __builtin_bit_cast(h2_t, __builtin_amdgcn_cvt_pkrtz(a, b));
}
__device__ __forceinline__ float fdot2(h2_t a, h2_t b, float c) {
    return __builtin_amdgcn_fdot2(a, b, c, false);
}

// ---- K1: q/k/v 1x1 convs (48 -> 3x64), output layout [b][y][x][c] ----
__global__ __launch_bounds__(256, 1) void k_qkv(const float* __restrict__ x,
    const float* __restrict__ wq, const float* __restrict__ bq,
    const float* __restrict__ wk, const float* __restrict__ bk,
    const float* __restrict__ wvw, const float* __restrict__ bv,
    float* __restrict__ q, float* __restrict__ k, float* __restrict__ v)
{
    __shared__ float xs[256][52];

    int tid = threadIdx.x;
    int blk = blockIdx.x;
    int b = blk / 144;
    int g0 = (blk % 144) * 256;
    const float* xb = x + (size_t)b * 48 * HWc + g0;

    #pragma unroll 8
    for (int c = 0; c < 48; ++c) xs[tid][c] = xb[(size_t)c * HWc + tid];

    int ln = tid & 63, wave = tid >> 6;
    float4 Wq[12], Wk[12], Wv[12];
    #pragma unroll
    for (int j = 0; j < 12; ++j) {
        Wq[j] = *(const float4*)(wq  + ln * 48 + j * 4);
        Wk[j] = *(const float4*)(wk  + ln * 48 + j * 4);
        Wv[j] = *(const float4*)(wvw + ln * 48 + j * 4);
    }
    float bqv = bq[ln], bkv = bk[ln], bvv = bv[ln];
    __syncthreads();

    size_t obase = ((size_t)b * HWc + g0) * 64 + ln;
    #pragma unroll 1
    for (int i = 0; i < 64; ++i) {
        int px = wave * 64 + i;
        float aq = bqv, ak = bkv, av = bvv;
        #pragma unroll
        for (int j = 0; j < 12; ++j) {
            float4 x4 = *(const float4*)&xs[px][j * 4];
            aq = fmaf(x4.x, Wq[j].x, aq); ak = fmaf(x4.x, Wk[j].x, ak); av = fmaf(x4.x, Wv[j].x, av);
            aq = fmaf(x4.y, Wq[j].y, aq); ak = fmaf(x4.y, Wk[j].y, ak); av = fmaf(x4.y, Wv[j].y, av);
            aq = fmaf(x4.z, Wq[j].z, aq); ak = fmaf(x4.z, Wk[j].z, ak); av = fmaf(x4.z, Wv[j].z, av);
            aq = fmaf(x4.w, Wq[j].w, aq); ak = fmaf(x4.w, Wk[j].w, ak); av = fmaf(x4.w, Wv[j].w, av);
        }
        q[obase + (size_t)px * 64] = aq;
        k[obase + (size_t)px * 64] = ak;
        v[obase + (size_t)px * 64] = av;
    }
}

// ------- K2: cond conv (68->17) + LayerNorm + leaky + channel-mean -------
__global__ __launch_bounds__(256) void k_cond(const float* __restrict__ vs,
    const float* __restrict__ cg,
    const float* __restrict__ w_in, const float* __restrict__ b_in,
    const float* __restrict__ ln_w, const float* __restrict__ ln_b,
    float* __restrict__ t, float* __restrict__ mpix)
{
    int g = blockIdx.x * 256 + threadIdx.x;
    int b = g / HWc, rem = g % HWc;
    int y = rem / Ww, xx = rem % Ww;

    float in[68];
    const float* vp = vs + (size_t)g * 64;
    #pragma unroll
    for (int c = 0; c < 64; c += 4) {
        float4 t4 = *(const float4*)(vp + c);
        in[c] = t4.x; in[c+1] = t4.y; in[c+2] = t4.z; in[c+3] = t4.w;
    }
    in[64] = cg[((size_t)b * 2 + 0) * HWc + rem];
    in[65] = cg[((size_t)b * 2 + 1) * HWc + rem];
    const float step = 2.0f / 7.0f;
    in[66] = -1.0f + step * (float)(y & 7);
    in[67] = -1.0f + step * (float)(xx & 7);

    float tv[17];
    float mu = 0.f;
    #pragma unroll
    for (int o = 0; o < 17; ++o) {
        float a = b_in[o];
        const float* wr = w_in + o * 68;
        #pragma unroll
        for (int c = 0; c < 68; ++c) a = fmaf(in[c], wr[c], a);
        tv[o] = a;
        mu += a;
    }
    mu *= (1.f / 17.f);
    float var = 0.f;
    #pragma unroll
    for (int o = 0; o < 17; ++o) { float d = tv[o] - mu; var = fmaf(d, d, var); }
    var *= (1.f / 17.f);
    float rstd = 1.f / sqrtf(var + 1e-6f);

    float msum = 0.f;
    #pragma unroll
    for (int o = 0; o < 17; ++o) {
        float z = (tv[o] - mu) * rstd * ln_w[o] + ln_b[o];
        z = (z >= 0.f) ? z : 0.1f * z;
        t[((size_t)b * 17 + o) * HWc + rem] = z;
        msum += z;
    }
    mpix[(size_t)b * HWc + rem] = msum * (1.f / 17.f);
}

// ---------------- K3: 3x3 conv (17->1) + sigmoid ----------------
__global__ __launch_bounds__(256) void k_sa(const float* __restrict__ t,
    const float* __restrict__ w_sa, const float* __restrict__ b_sa,
    float* __restrict__ sa)
{
    int g = blockIdx.x * 256 + threadIdx.x;
    int b = g / HWc, rem = g % HWc;
    int y = rem / Ww, xx = rem % Ww;

    float a = b_sa[0];
    for (int c = 0; c < 17; ++c) {
        const float* tp = t + ((size_t)b * 17 + c) * HWc;
        const float* wr = w_sa + c * 9;
        #pragma unroll
        for (int ki = 0; ki < 3; ++ki) {
            int yy = y + ki - 1;
            if ((unsigned)yy >= 192u) continue;
            #pragma unroll
            for (int kj = 0; kj < 3; ++kj) {
                int xc = xx + kj - 1;
                if ((unsigned)xc >= 192u) continue;
                a = fmaf(tp[yy * Ww + xc], wr[ki * 3 + kj], a);
            }
        }
    }
    sa[g] = 1.f / (1.f + expf(-a));
}

// -------- K4: window score MLP + stable descending rank -> flag --------
__global__ __launch_bounds__(576) void k_score(const float* __restrict__ mpix,
    const float* __restrict__ w_m1, const float* __restrict__ b_m1,
    const float* __restrict__ w_m2, const float* __restrict__ b_m2,
    int* __restrict__ flag)
{
    __shared__ float sc[NWc];
    int b = blockIdx.x;
    int w = threadIdx.x;
    {
        int hy = w / WNc, wx = w % WNc;
        const float* mp = mpix + (size_t)b * HWc + (hy * 8) * Ww + wx * 8;
        float m[64];
        #pragma unroll
        for (int l = 0; l < 64; ++l) m[l] = mp[(l >> 3) * Ww + (l & 7)];
        float h1[8];
        #pragma unroll
        for (int j = 0; j < 8; ++j) {
            float a = b_m1[j];
            const float* wr = w_m1 + j * 64;
            #pragma unroll
            for (int l = 0; l < 64; ++l) a = fmaf(m[l], wr[l], a);
            h1[j] = (a >= 0.f) ? a : 0.1f * a;
        }
        float l0 = b_m2[0], l1 = b_m2[1];
        #pragma unroll
        for (int j = 0; j < 8; ++j) {
            l0 = fmaf(h1[j], w_m2[j], l0);
            l1 = fmaf(h1[j], w_m2[8 + j], l1);
        }
        float mx = fmaxf(l0, l1);
        float e0 = expf(l0 - mx), e1 = expf(l1 - mx);
        sc[w] = e0 / (e0 + e1);
    }
    __syncthreads();
    float s = sc[w];
    int cnt = 0;
    for (int w2 = 0; w2 < NWc; ++w2) {
        float s2 = sc[w2];
        cnt += ((s2 > s) || (s2 == s && w2 < w)) ? 1 : 0;
    }
    flag[b * NWc + w] = (cnt < NKc) ? 1 : 0;
}

// ---- K5: per-window attention, f16 K/V in LDS, fdot2 inner loops ----
// LDS 36.9 KB -> 4 blocks/CU. K: [144 px][64 ch] halves. V: [72 keypair][64 ch]
// h2 (pair = consecutive keys) so PV is fdot2((e0,e1),(v0[d],v1[d])).
__global__ __launch_bounds__(256) void k_attn(const float* __restrict__ qs,
    const float* __restrict__ ks, const float* __restrict__ vsb,
    const float* __restrict__ sab, const int* __restrict__ flag,
    const float* __restrict__ relh, const float* __restrict__ relw,
    const float* __restrict__ w_out, const float* __restrict__ b_out,
    float* __restrict__ out)
{
    __shared__ __align__(16) unsigned char smem[36864];
    unsigned char* smemK = smem;            // 18432 B
    unsigned char* smemV = smem + 18432;    // 18432 B
    float (*mlds)[65] = (float (*)[65])smem; // 16640 B, aliases smemK

    int tid = threadIdx.x;
    int blk = blockIdx.x;
    int b = blk / NWc, n = blk % NWc;
    int hy = n / WNc, wx = n % WNc;
    int y0 = hy * 8, x0 = wx * 8;

    if (flag[b * NWc + n]) {
        // ---- stage 12x12x64 K,V as f16, zero-filled OOB ----
        #pragma unroll
        for (int i = 0; i < 9; ++i) {
            int idx = i * 256 + tid;          // 144 px * 16 chunks
            int px = idx >> 4, c4 = idx & 15;
            int py = px / 12, pxx = px - py * 12;
            int ky = y0 - 2 + py, kx = x0 - 2 + pxx;
            bool ok = ((unsigned)ky < 192u) && ((unsigned)kx < 192u);
            int kyc = min(max(ky, 0), 191), kxc = min(max(kx, 0), 191);
            size_t goff = ((size_t)(b * HWc) + kyc * Ww + kxc) * 64 + c4 * 4;
            float4 k4 = *(const float4*)(ks + goff);
            float4 v4 = *(const float4*)(vsb + goff);
            if (!ok) { k4 = make_float4(0,0,0,0); v4 = make_float4(0,0,0,0); }
            h2_t k0 = pkrtz(k4.x, k4.y);
            h2_t k1 = pkrtz(k4.z, k4.w);
            *(uint2*)(smemK + px * 128 + c4 * 8) = make_uint2(h2u(k0), h2u(k1));
            _Float16* vh = (_Float16*)smemV;
            int vbase = (px >> 1) * 128 + (px & 1);
            vh[vbase + (c4*4+0)*2] = (_Float16)v4.x;
            vh[vbase + (c4*4+1)*2] = (_Float16)v4.y;
            vh[vbase + (c4*4+2)*2] = (_Float16)v4.z;
            vh[vbase + (c4*4+3)*2] = (_Float16)v4.w;
        }
        __syncthreads();

        int h = __builtin_amdgcn_readfirstlane(tid >> 6);  // head, SGPR
        int l = tid & 63;
        int qr = l >> 3, qc = l & 7;

        const float* qp = qs + ((size_t)(b * HWc) + (y0 + qr) * Ww + (x0 + qc)) * 64 + h * 16;
        float qv[16];
        #pragma unroll
        for (int j = 0; j < 4; ++j) {
            float4 t4 = *(const float4*)(qp + j * 4);
            qv[j*4+0] = t4.x; qv[j*4+1] = t4.y; qv[j*4+2] = t4.z; qv[j*4+3] = t4.w;
        }
        // packed q (scaled by 0.25 here so logits = rel + dot_f16)
        h2_t qh[8];
        #pragma unroll
        for (int j = 0; j < 8; ++j)
            qh[j] = pkrtz(0.25f * qv[2*j], 0.25f * qv[2*j+1]);

        // relative-position logit tables (f32 q; rel idx in [4,22] valid)
        float rw[12], rh[12];
        #pragma unroll
        for (int kc = 0; kc < 12; ++kc) {
            const float* rp = relw + (kc - qc + 11) * 16;
            float a = 0.f;
            #pragma unroll
            for (int j = 0; j < 4; ++j) {
                float4 t4 = *(const float4*)(rp + j * 4);
                a = fmaf(qv[j*4+0], t4.x, a); a = fmaf(qv[j*4+1], t4.y, a);
                a = fmaf(qv[j*4+2], t4.z, a); a = fmaf(qv[j*4+3], t4.w, a);
            }
            rw[kc] = a;
        }
        #pragma unroll
        for (int kr = 0; kr < 12; ++kr) {
            const float* rp = relh + (kr - qr + 11) * 16;
            float a = 0.f;
            #pragma unroll
            for (int j = 0; j < 4; ++j) {
                float4 t4 = *(const float4*)(rp + j * 4);
                a = fmaf(qv[j*4+0], t4.x, a); a = fmaf(qv[j*4+1], t4.y, a);
                a = fmaf(qv[j*4+2], t4.z, a); a = fmaf(qv[j*4+3], t4.w, a);
            }
            rh[kr] = a;
        }

        float mw = rw[0], mh = rh[0];
        #pragma unroll
        for (int i = 1; i < 12; ++i) { mw = fmaxf(mw, rw[i]); mh = fmaxf(mh, rh[i]); }
        float mrel = mw + mh;

        float lsum = 0.f;
        float acc[16];
        #pragma unroll
        for (int d = 0; d < 16; ++d) acc[d] = 0.f;

        // ---- 72 key-pairs: QK via fdot2, PV via paired fdot2 ----
        #pragma unroll 1
        for (int kr = 0; kr < 12; ++kr) {
            float rhv = rh[kr] - mrel;
            #pragma unroll 3
            for (int pc = 0; pc < 6; ++pc) {
                int kk = kr * 12 + pc * 2;
                const uint4* k0p = (const uint4*)(smemK + (size_t)kk * 128 + h * 32);
                const uint4* k1p = (const uint4*)(smemK + (size_t)(kk+1) * 128 + h * 32);
                uint4 ka = k0p[0], kb = k0p[1];
                uint4 kc4 = k1p[0], kd = k1p[1];
                float d0 = 0.f, d1 = 0.f;
                d0 = fdot2(qh[0], u2h(ka.x), d0); d0 = fdot2(qh[1], u2h(ka.y), d0);
                d0 = fdot2(qh[2], u2h(ka.z), d0); d0 = fdot2(qh[3], u2h(ka.w), d0);
                d0 = fdot2(qh[4], u2h(kb.x), d0); d0 = fdot2(qh[5], u2h(kb.y), d0);
                d0 = fdot2(qh[6], u2h(kb.z), d0); d0 = fdot2(qh[7], u2h(kb.w), d0);
                d1 = fdot2(qh[0], u2h(kc4.x), d1); d1 = fdot2(qh[1], u2h(kc4.y), d1);
                d1 = fdot2(qh[2], u2h(kc4.z), d1); d1 = fdot2(qh[3], u2h(kc4.w), d1);
                d1 = fdot2(qh[4], u2h(kd.x), d1); d1 = fdot2(qh[5], u2h(kd.y), d1);
                d1 = fdot2(qh[6], u2h(kd.z), d1); d1 = fdot2(qh[7], u2h(kd.w), d1);
                float e0 = __expf(rw[pc*2+0] + rhv + d0);
                float e1 = __expf(rw[pc*2+1] + rhv + d1);
                lsum += e0 + e1;
                h2_t e2 = pkrtz(e0, e1);
                int kp = kr * 6 + pc;
                const uint4* vrow = (const uint4*)(smemV + (size_t)kp * 256 + h * 64);
                uint4 va = vrow[0], vb = vrow[1], vc = vrow[2], vd = vrow[3];
                acc[0]  = fdot2(e2, u2h(va.x), acc[0]);  acc[1]  = fdot2(e2, u2h(va.y), acc[1]);
                acc[2]  = fdot2(e2, u2h(va.z), acc[2]);  acc[3]  = fdot2(e2, u2h(va.w), acc[3]);
                acc[4]  = fdot2(e2, u2h(vb.x), acc[4]);  acc[5]  = fdot2(e2, u2h(vb.y), acc[5]);
                acc[6]  = fdot2(e2, u2h(vb.z), acc[6]);  acc[7]  = fdot2(e2, u2h(vb.w), acc[7]);
                acc[8]  = fdot2(e2, u2h(vc.x), acc[8]);  acc[9]  = fdot2(e2, u2h(vc.y), acc[9]);
                acc[10] = fdot2(e2, u2h(vc.z), acc[10]); acc[11] = fdot2(e2, u2h(vc.w), acc[11]);
                acc[12] = fdot2(e2, u2h(vd.x), acc[12]); acc[13] = fdot2(e2, u2h(vd.y), acc[13]);
                acc[14] = fdot2(e2, u2h(vd.z), acc[14]); acc[15] = fdot2(e2, u2h(vd.w), acc[15]);
            }
        }
        __syncthreads();   // done reading smemK before aliased mlds write
        float inv = 1.f / lsum;
        #pragma unroll
        for (int d = 0; d < 16; ++d) mlds[l][h * 16 + d] = acc[d] * inv;
    } else {
        // easy path: vs * sa
        int l = tid >> 2, part = tid & 3;
        int gy = y0 + (l >> 3), gx = x0 + (l & 7);
        const float* vp = vsb + ((size_t)(b * HWc) + gy * Ww + gx) * 64 + part * 16;
        float sv = sab[(size_t)b * HWc + gy * Ww + gx];
        #pragma unroll
        for (int j = 0; j < 4; ++j) {
            float4 v4 = *(const float4*)(vp + j * 4);
            mlds[l][part*16 + j*4 + 0] = v4.x * sv;
            mlds[l][part*16 + j*4 + 1] = v4.y * sv;
            mlds[l][part*16 + j*4 + 2] = v4.z * sv;
            mlds[l][part*16 + j*4 + 3] = v4.w * sv;
        }
    }
    __syncthreads();

    // fused output conv: 64 -> 48 per pixel (wave-uniform weight s_loads)
    {
        int l = tid & 63;
        int og = __builtin_amdgcn_readfirstlane(tid >> 6);
        int gy = y0 + (l >> 3), gx = x0 + (l & 7);
        float mv[64];
        #pragma unroll
        for (int c = 0; c < 64; ++c) mv[c] = mlds[l][c];
        #pragma unroll 1
        for (int j = 0; j < 12; ++j) {
            int oc = og * 12 + j;
            float a = b_out[oc];
            const float* wr = w_out + oc * 64;
            #pragma unroll
            for (int c = 0; c < 64; ++c) a = fmaf(mv[c], wr[c], a);
            out[((size_t)(b * 48 + oc)) * HWc + gy * Ww + gx] = a;
        }
    }
}

extern "C" void kernel_launch(void* const* d_in, const int* in_sizes, int n_in,
                              void* d_out, int out_size, void* d_ws, size_t ws_size,
                              hipStream_t stream)
{
    const float* x    = (const float*)d_in[0];
    const float* cg   = (const float*)d_in[1];
    const float* wq   = (const float*)d_in[2];
    const float* bq   = (const float*)d_in[3];
    const float* wk   = (const float*)d_in[4];
    const float* bk   = (const float*)d_in[5];
    const float* wv   = (const float*)d_in[6];
    const float* bv   = (const float*)d_in[7];
    const float* w_in = (const float*)d_in[8];
    const float* b_in = (const float*)d_in[9];
    const float* ln_w = (const float*)d_in[10];
    const float* ln_b = (const float*)d_in[11];
    const float* w_sa = (const float*)d_in[12];
    const float* b_sa = (const float*)d_in[13];
    const float* w_m1 = (const float*)d_in[14];
    const float* b_m1 = (const float*)d_in[15];
    const float* w_m2 = (const float*)d_in[16];
    const float* b_m2 = (const float*)d_in[17];
    const float* rel_h= (const float*)d_in[18];
    const float* rel_w= (const float*)d_in[19];
    const float* w_out= (const float*)d_in[20];
    const float* b_out= (const float*)d_in[21];
    float* out = (float*)d_out;

    float* ws   = (float*)d_ws;
    float* qs   = ws;
    float* ks   = qs + (size_t)Bc * 64 * HWc;
    float* vs   = ks + (size_t)Bc * 64 * HWc;
    float* t    = vs + (size_t)Bc * 64 * HWc;
    float* sa   = t  + (size_t)Bc * 17 * HWc;
    float* mpix = sa + (size_t)Bc * HWc;
    int*   flag = (int*)(mpix + (size_t)Bc * HWc);

    k_qkv  <<<576, 256, 0, stream>>>(x, wq, bq, wk, bk, wv, bv, qs, ks, vs);
    k_cond <<<576, 256, 0, stream>>>(vs, cg, w_in, b_in, ln_w, ln_b, t, mpix);
    k_sa   <<<576, 256, 0, stream>>>(t, w_sa, b_sa, sa);
    k_score<<<4, 576, 0, stream>>>(mpix, w_m1, b_m1, w_m2, b_m2, flag);
    k_attn <<<2304, 256, 0, stream>>>(qs, ks, vs, sa, flag, rel_h, rel_w, w_out, b_out, out);
}

// Round 9
// 233.195 us; speedup vs baseline: 4.7583x; 1.2579x over previous
//
#include <hip/hip_runtime.h>
#include <math.h>

#define Hh 192
#define Ww 192
#define HWc 36864
#define Bc 4
#define NWc 576
#define NKc 288
#define WNc 24

typedef _Float16 h2_t __attribute__((ext_vector_type(2)));
__device__ __forceinline__ h2_t u2h(unsigned u) { return __builtin_bit_cast(h2_t, u); }
__device__ __forceinline__ unsigned h2u(h2_t h) { return __builtin_bit_cast(unsigned, h); }
__device__ __forceinline__ h2_t pkrtz(float a, float b) {
    return __builtin_bit_cast(h2_t, __builtin_amdgcn_cvt_pkrtz(a, b));
}
__device__ __forceinline__ float fdot2(h2_t a, h2_t b, float c) {
    return __builtin_amdgcn_fdot2(a, b, c, false);
}

// ---- K1: q/k/v 1x1 convs (48 -> 3x64), output layout [b][y][x][c] ----
// lane = out-channel, weights in VGPRs; 128 px/block (1152 blocks for TLP);
// pixel loop is 2-deep software-pipelined: next pixel's 12 ds_read_b128
// issue before current pixel's 144 FMAs, hiding LDS latency under compute.
__global__ __launch_bounds__(256, 1) void k_qkv(const float* __restrict__ x,
    const float* __restrict__ wq, const float* __restrict__ bq,
    const float* __restrict__ wk, const float* __restrict__ bk,
    const float* __restrict__ wvw, const float* __restrict__ bv,
    float* __restrict__ q, float* __restrict__ k, float* __restrict__ v)
{
    __shared__ float xs[132][52];      // 128 px (+4 pad rows for prefetch OOB)

    int tid = threadIdx.x;
    int blk = blockIdx.x;
    int b = blk / 288;
    int g0 = (blk % 288) * 128;
    const float* xb = x + (size_t)b * 48 * HWc + g0;

    // stage x: i = c*128+px so lanes are px-consecutive (coalesced)
    #pragma unroll
    for (int it = 0; it < 24; ++it) {
        int i = it * 256 + tid;
        int c = i >> 7, px = i & 127;
        xs[px][c] = xb[(size_t)c * HWc + px];
    }

    int ln = tid & 63, wave = tid >> 6;
    float4 Wq[12], Wk[12], Wv[12];
    #pragma unroll
    for (int j = 0; j < 12; ++j) {
        Wq[j] = *(const float4*)(wq  + ln * 48 + j * 4);
        Wk[j] = *(const float4*)(wk  + ln * 48 + j * 4);
        Wv[j] = *(const float4*)(wvw + ln * 48 + j * 4);
    }
    float bqv = bq[ln], bkv = bk[ln], bvv = bv[ln];
    __syncthreads();

    int p0 = wave * 32;
    size_t obase = ((size_t)b * HWc + g0) * 64 + ln;

#define QKV_COMPUTE(XBUF, PX)                                                              \
    {                                                                                      \
        float aq = bqv, ak = bkv, av = bvv;                                                \
        _Pragma("unroll")                                                                  \
        for (int j = 0; j < 12; ++j) {                                                     \
            float4 x4 = XBUF[j];                                                           \
            aq = fmaf(x4.x, Wq[j].x, aq); ak = fmaf(x4.x, Wk[j].x, ak); av = fmaf(x4.x, Wv[j].x, av); \
            aq = fmaf(x4.y, Wq[j].y, aq); ak = fmaf(x4.y, Wk[j].y, ak); av = fmaf(x4.y, Wv[j].y, av); \
            aq = fmaf(x4.z, Wq[j].z, aq); ak = fmaf(x4.z, Wk[j].z, ak); av = fmaf(x4.z, Wv[j].z, av); \
            aq = fmaf(x4.w, Wq[j].w, aq); ak = fmaf(x4.w, Wk[j].w, ak); av = fmaf(x4.w, Wv[j].w, av); \
        }                                                                                  \
        q[obase + (size_t)(PX) * 64] = aq;                                                 \
        k[obase + (size_t)(PX) * 64] = ak;                                                 \
        v[obase + (size_t)(PX) * 64] = av;                                                 \
    }

    float4 XA[12], XB[12];
    #pragma unroll
    for (int j = 0; j < 12; ++j) XA[j] = *(const float4*)&xs[p0][j * 4];

    #pragma unroll 1
    for (int i = 0; i < 32; i += 2) {
        int pxA = p0 + i;
        #pragma unroll
        for (int j = 0; j < 12; ++j) XB[j] = *(const float4*)&xs[pxA + 1][j * 4];
        QKV_COMPUTE(XA, pxA);
        #pragma unroll
        for (int j = 0; j < 12; ++j) XA[j] = *(const float4*)&xs[pxA + 2][j * 4];
        QKV_COMPUTE(XB, pxA + 1);
    }
#undef QKV_COMPUTE
}

// ------- K2: cond conv (68->17) + LayerNorm + leaky + channel-mean -------
__global__ __launch_bounds__(256) void k_cond(const float* __restrict__ vs,
    const float* __restrict__ cg,
    const float* __restrict__ w_in, const float* __restrict__ b_in,
    const float* __restrict__ ln_w, const float* __restrict__ ln_b,
    float* __restrict__ t, float* __restrict__ mpix)
{
    int g = blockIdx.x * 256 + threadIdx.x;
    int b = g / HWc, rem = g % HWc;
    int y = rem / Ww, xx = rem % Ww;

    float in[68];
    const float* vp = vs + (size_t)g * 64;
    #pragma unroll
    for (int c = 0; c < 64; c += 4) {
        float4 t4 = *(const float4*)(vp + c);
        in[c] = t4.x; in[c+1] = t4.y; in[c+2] = t4.z; in[c+3] = t4.w;
    }
    in[64] = cg[((size_t)b * 2 + 0) * HWc + rem];
    in[65] = cg[((size_t)b * 2 + 1) * HWc + rem];
    const float step = 2.0f / 7.0f;
    in[66] = -1.0f + step * (float)(y & 7);
    in[67] = -1.0f + step * (float)(xx & 7);

    float tv[17];
    float mu = 0.f;
    #pragma unroll
    for (int o = 0; o < 17; ++o) {
        float a = b_in[o];
        const float* wr = w_in + o * 68;
        #pragma unroll
        for (int c = 0; c < 68; ++c) a = fmaf(in[c], wr[c], a);
        tv[o] = a;
        mu += a;
    }
    mu *= (1.f / 17.f);
    float var = 0.f;
    #pragma unroll
    for (int o = 0; o < 17; ++o) { float d = tv[o] - mu; var = fmaf(d, d, var); }
    var *= (1.f / 17.f);
    float rstd = 1.f / sqrtf(var + 1e-6f);

    float msum = 0.f;
    #pragma unroll
    for (int o = 0; o < 17; ++o) {
        float z = (tv[o] - mu) * rstd * ln_w[o] + ln_b[o];
        z = (z >= 0.f) ? z : 0.1f * z;
        t[((size_t)b * 17 + o) * HWc + rem] = z;
        msum += z;
    }
    mpix[(size_t)b * HWc + rem] = msum * (1.f / 17.f);
}

// ---------------- K3: 3x3 conv (17->1) + sigmoid ----------------
__global__ __launch_bounds__(256) void k_sa(const float* __restrict__ t,
    const float* __restrict__ w_sa, const float* __restrict__ b_sa,
    float* __restrict__ sa)
{
    int g = blockIdx.x * 256 + threadIdx.x;
    int b = g / HWc, rem = g % HWc;
    int y = rem / Ww, xx = rem % Ww;

    float a = b_sa[0];
    for (int c = 0; c < 17; ++c) {
        const float* tp = t + ((size_t)b * 17 + c) * HWc;
        const float* wr = w_sa + c * 9;
        #pragma unroll
        for (int ki = 0; ki < 3; ++ki) {
            int yy = y + ki - 1;
            if ((unsigned)yy >= 192u) continue;
            #pragma unroll
            for (int kj = 0; kj < 3; ++kj) {
                int xc = xx + kj - 1;
                if ((unsigned)xc >= 192u) continue;
                a = fmaf(tp[yy * Ww + xc], wr[ki * 3 + kj], a);
            }
        }
    }
    sa[g] = 1.f / (1.f + expf(-a));
}

// -------- K4: window score MLP + stable descending rank -> flag --------
__global__ __launch_bounds__(576) void k_score(const float* __restrict__ mpix,
    const float* __restrict__ w_m1, const float* __restrict__ b_m1,
    const float* __restrict__ w_m2, const float* __restrict__ b_m2,
    int* __restrict__ flag)
{
    __shared__ float sc[NWc];
    int b = blockIdx.x;
    int w = threadIdx.x;
    {
        int hy = w / WNc, wx = w % WNc;
        const float* mp = mpix + (size_t)b * HWc + (hy * 8) * Ww + wx * 8;
        float m[64];
        #pragma unroll
        for (int l = 0; l < 64; ++l) m[l] = mp[(l >> 3) * Ww + (l & 7)];
        float h1[8];
        #pragma unroll
        for (int j = 0; j < 8; ++j) {
            float a = b_m1[j];
            const float* wr = w_m1 + j * 64;
            #pragma unroll
            for (int l = 0; l < 64; ++l) a = fmaf(m[l], wr[l], a);
            h1[j] = (a >= 0.f) ? a : 0.1f * a;
        }
        float l0 = b_m2[0], l1 = b_m2[1];
        #pragma unroll
        for (int j = 0; j < 8; ++j) {
            l0 = fmaf(h1[j], w_m2[j], l0);
            l1 = fmaf(h1[j], w_m2[8 + j], l1);
        }
        float mx = fmaxf(l0, l1);
        float e0 = expf(l0 - mx), e1 = expf(l1 - mx);
        sc[w] = e0 / (e0 + e1);
    }
    __syncthreads();
    float s = sc[w];
    int cnt = 0;
    for (int w2 = 0; w2 < NWc; ++w2) {
        float s2 = sc[w2];
        cnt += ((s2 > s) || (s2 == s && w2 < w)) ? 1 : 0;
    }
    flag[b * NWc + w] = (cnt < NKc) ? 1 : 0;
}

// ---- K5: per-window attention, f16 K/V in LDS, fdot2 inner loops ----
__global__ __launch_bounds__(256) void k_attn(const float* __restrict__ qs,
    const float* __restrict__ ks, const float* __restrict__ vsb,
    const float* __restrict__ sab, const int* __restrict__ flag,
    const float* __restrict__ relh, const float* __restrict__ relw,
    const float* __restrict__ w_out, const float* __restrict__ b_out,
    float* __restrict__ out)
{
    __shared__ __align__(16) unsigned char smem[36864];
    unsigned char* smemK = smem;            // 18432 B
    unsigned char* smemV = smem + 18432;    // 18432 B
    float (*mlds)[65] = (float (*)[65])smem; // 16640 B, aliases smemK

    int tid = threadIdx.x;
    int blk = blockIdx.x;
    int b = blk / NWc, n = blk % NWc;
    int hy = n / WNc, wx = n % WNc;
    int y0 = hy * 8, x0 = wx * 8;

    if (flag[b * NWc + n]) {
        // ---- stage 12x12x64 K,V as f16, zero-filled OOB ----
        #pragma unroll
        for (int i = 0; i < 9; ++i) {
            int idx = i * 256 + tid;          // 144 px * 16 chunks
            int px = idx >> 4, c4 = idx & 15;
            int py = px / 12, pxx = px - py * 12;
            int ky = y0 - 2 + py, kx = x0 - 2 + pxx;
            bool ok = ((unsigned)ky < 192u) && ((unsigned)kx < 192u);
            int kyc = min(max(ky, 0), 191), kxc = min(max(kx, 0), 191);
            size_t goff = ((size_t)(b * HWc) + kyc * Ww + kxc) * 64 + c4 * 4;
            float4 k4 = *(const float4*)(ks + goff);
            float4 v4 = *(const float4*)(vsb + goff);
            if (!ok) { k4 = make_float4(0,0,0,0); v4 = make_float4(0,0,0,0); }
            h2_t k0 = pkrtz(k4.x, k4.y);
            h2_t k1 = pkrtz(k4.z, k4.w);
            *(uint2*)(smemK + px * 128 + c4 * 8) = make_uint2(h2u(k0), h2u(k1));
            _Float16* vh = (_Float16*)smemV;
            int vbase = (px >> 1) * 128 + (px & 1);
            vh[vbase + (c4*4+0)*2] = (_Float16)v4.x;
            vh[vbase + (c4*4+1)*2] = (_Float16)v4.y;
            vh[vbase + (c4*4+2)*2] = (_Float16)v4.z;
            vh[vbase + (c4*4+3)*2] = (_Float16)v4.w;
        }
        __syncthreads();

        int h = __builtin_amdgcn_readfirstlane(tid >> 6);  // head, SGPR
        int l = tid & 63;
        int qr = l >> 3, qc = l & 7;

        const float* qp = qs + ((size_t)(b * HWc) + (y0 + qr) * Ww + (x0 + qc)) * 64 + h * 16;
        float qv[16];
        #pragma unroll
        for (int j = 0; j < 4; ++j) {
            float4 t4 = *(const float4*)(qp + j * 4);
            qv[j*4+0] = t4.x; qv[j*4+1] = t4.y; qv[j*4+2] = t4.z; qv[j*4+3] = t4.w;
        }
        // packed q (scaled by 0.25 here so logits = rel + dot_f16)
        h2_t qh[8];
        #pragma unroll
        for (int j = 0; j < 8; ++j)
            qh[j] = pkrtz(0.25f * qv[2*j], 0.25f * qv[2*j+1]);

        // relative-position logit tables (f32 q; rel idx in [4,22] valid)
        float rw[12], rh[12];
        #pragma unroll
        for (int kc = 0; kc < 12; ++kc) {
            const float* rp = relw + (kc - qc + 11) * 16;
            float a = 0.f;
            #pragma unroll
            for (int j = 0; j < 4; ++j) {
                float4 t4 = *(const float4*)(rp + j * 4);
                a = fmaf(qv[j*4+0], t4.x, a); a = fmaf(qv[j*4+1], t4.y, a);
                a = fmaf(qv[j*4+2], t4.z, a); a = fmaf(qv[j*4+3], t4.w, a);
            }
            rw[kc] = a;
        }
        #pragma unroll
        for (int kr = 0; kr < 12; ++kr) {
            const float* rp = relh + (kr - qr + 11) * 16;
            float a = 0.f;
            #pragma unroll
            for (int j = 0; j < 4; ++j) {
                float4 t4 = *(const float4*)(rp + j * 4);
                a = fmaf(qv[j*4+0], t4.x, a); a = fmaf(qv[j*4+1], t4.y, a);
                a = fmaf(qv[j*4+2], t4.z, a); a = fmaf(qv[j*4+3], t4.w, a);
            }
            rh[kr] = a;
        }

        float mw = rw[0], mh = rh[0];
        #pragma unroll
        for (int i = 1; i < 12; ++i) { mw = fmaxf(mw, rw[i]); mh = fmaxf(mh, rh[i]); }
        float mrel = mw + mh;

        float lsum = 0.f;
        float acc[16];
        #pragma unroll
        for (int d = 0; d < 16; ++d) acc[d] = 0.f;

        // ---- 72 key-pairs: QK via fdot2, PV via paired fdot2 ----
        #pragma unroll 1
        for (int kr = 0; kr < 12; ++kr) {
            float rhv = rh[kr] - mrel;
            #pragma unroll 3
            for (int pc = 0; pc < 6; ++pc) {
                int kk = kr * 12 + pc * 2;
                const uint4* k0p = (const uint4*)(smemK + (size_t)kk * 128 + h * 32);
                const uint4* k1p = (const uint4*)(smemK + (size_t)(kk+1) * 128 + h * 32);
                uint4 ka = k0p[0], kb = k0p[1];
                uint4 kc4 = k1p[0], kd = k1p[1];
                float d0 = 0.f, d1 = 0.f;
                d0 = fdot2(qh[0], u2h(ka.x), d0); d0 = fdot2(qh[1], u2h(ka.y), d0);
                d0 = fdot2(qh[2], u2h(ka.z), d0); d0 = fdot2(qh[3], u2h(ka.w), d0);
                d0 = fdot2(qh[4], u2h(kb.x), d0); d0 = fdot2(qh[5], u2h(kb.y), d0);
                d0 = fdot2(qh[6], u2h(kb.z), d0); d0 = fdot2(qh[7], u2h(kb.w), d0);
                d1 = fdot2(qh[0], u2h(kc4.x), d1); d1 = fdot2(qh[1], u2h(kc4.y), d1);
                d1 = fdot2(qh[2], u2h(kc4.z), d1); d1 = fdot2(qh[3], u2h(kc4.w), d1);
                d1 = fdot2(qh[4], u2h(kd.x), d1); d1 = fdot2(qh[5], u2h(kd.y), d1);
                d1 = fdot2(qh[6], u2h(kd.z), d1); d1 = fdot2(qh[7], u2h(kd.w), d1);
                float e0 = __expf(rw[pc*2+0] + rhv + d0);
                float e1 = __expf(rw[pc*2+1] + rhv + d1);
                lsum += e0 + e1;
                h2_t e2 = pkrtz(e0, e1);
                int kp = kr * 6 + pc;
                const uint4* vrow = (const uint4*)(smemV + (size_t)kp * 256 + h * 64);
                uint4 va = vrow[0], vb = vrow[1], vc = vrow[2], vd = vrow[3];
                acc[0]  = fdot2(e2, u2h(va.x), acc[0]);  acc[1]  = fdot2(e2, u2h(va.y), acc[1]);
                acc[2]  = fdot2(e2, u2h(va.z), acc[2]);  acc[3]  = fdot2(e2, u2h(va.w), acc[3]);
                acc[4]  = fdot2(e2, u2h(vb.x), acc[4]);  acc[5]  = fdot2(e2, u2h(vb.y), acc[5]);
                acc[6]  = fdot2(e2, u2h(vb.z), acc[6]);  acc[7]  = fdot2(e2, u2h(vb.w), acc[7]);
                acc[8]  = fdot2(e2, u2h(vc.x), acc[8]);  acc[9]  = fdot2(e2, u2h(vc.y), acc[9]);
                acc[10] = fdot2(e2, u2h(vc.z), acc[10]); acc[11] = fdot2(e2, u2h(vc.w), acc[11]);
                acc[12] = fdot2(e2, u2h(vd.x), acc[12]); acc[13] = fdot2(e2, u2h(vd.y), acc[13]);
                acc[14] = fdot2(e2, u2h(vd.z), acc[14]); acc[15] = fdot2(e2, u2h(vd.w), acc[15]);
            }
        }
        __syncthreads();   // done reading smemK before aliased mlds write
        float inv = 1.f / lsum;
        #pragma unroll
        for (int d = 0; d < 16; ++d) mlds[l][h * 16 + d] = acc[d] * inv;
    } else {
        // easy path: vs * sa
        int l = tid >> 2, part = tid & 3;
        int gy = y0 + (l >> 3), gx = x0 + (l & 7);
        const float* vp = vsb + ((size_t)(b * HWc) + gy * Ww + gx) * 64 + part * 16;
        float sv = sab[(size_t)b * HWc + gy * Ww + gx];
        #pragma unroll
        for (int j = 0; j < 4; ++j) {
            float4 v4 = *(const float4*)(vp + j * 4);
            mlds[l][part*16 + j*4 + 0] = v4.x * sv;
            mlds[l][part*16 + j*4 + 1] = v4.y * sv;
            mlds[l][part*16 + j*4 + 2] = v4.z * sv;
            mlds[l][part*16 + j*4 + 3] = v4.w * sv;
        }
    }
    __syncthreads();

    // fused output conv: 64 -> 48 per pixel (wave-uniform weight s_loads)
    {
        int l = tid & 63;
        int og = __builtin_amdgcn_readfirstlane(tid >> 6);
        int gy = y0 + (l >> 3), gx = x0 + (l & 7);
        float mv[64];
        #pragma unroll
        for (int c = 0; c < 64; ++c) mv[c] = mlds[l][c];
        #pragma unroll 1
        for (int j = 0; j < 12; ++j) {
            int oc = og * 12 + j;
            float a = b_out[oc];
            const float* wr = w_out + oc * 64;
            #pragma unroll
            for (int c = 0; c < 64; ++c) a = fmaf(mv[c], wr[c], a);
            out[((size_t)(b * 48 + oc)) * HWc + gy * Ww + gx] = a;
        }
    }
}

extern "C" void kernel_launch(void* const* d_in, const int* in_sizes, int n_in,
                              void* d_out, int out_size, void* d_ws, size_t ws_size,
                              hipStream_t stream)
{
    const float* x    = (const float*)d_in[0];
    const float* cg   = (const float*)d_in[1];
    const float* wq   = (const float*)d_in[2];
    const float* bq   = (const float*)d_in[3];
    const float* wk   = (const float*)d_in[4];
    const float* bk   = (const float*)d_in[5];
    const float* wv   = (const float*)d_in[6];
    const float* bv   = (const float*)d_in[7];
    const float* w_in = (const float*)d_in[8];
    const float* b_in = (const float*)d_in[9];
    const float* ln_w = (const float*)d_in[10];
    const float* ln_b = (const float*)d_in[11];
    const float* w_sa = (const float*)d_in[12];
    const float* b_sa = (const float*)d_in[13];
    const float* w_m1 = (const float*)d_in[14];
    const float* b_m1 = (const float*)d_in[15];
    const float* w_m2 = (const float*)d_in[16];
    const float* b_m2 = (const float*)d_in[17];
    const float* rel_h= (const float*)d_in[18];
    const float* rel_w= (const float*)d_in[19];
    const float* w_out= (const float*)d_in[20];
    const float* b_out= (const float*)d_in[21];
    float* out = (float*)d_out;

    float* ws   = (float*)d_ws;
    float* qs   = ws;
    float* ks   = qs + (size_t)Bc * 64 * HWc;
    float* vs   = ks + (size_t)Bc * 64 * HWc;
    float* t    = vs + (size_t)Bc * 64 * HWc;
    float* sa   = t  + (size_t)Bc * 17 * HWc;
    float* mpix = sa + (size_t)Bc * HWc;
    int*   flag = (int*)(mpix + (size_t)Bc * HWc);

    k_qkv  <<<1152, 256, 0, stream>>>(x, wq, bq, wk, bk, wv, bv, qs, ks, vs);
    k_cond <<<576, 256, 0, stream>>>(vs, cg, w_in, b_in, ln_w, ln_b, t, mpix);
    k_sa   <<<576, 256, 0, stream>>>(t, w_sa, b_sa, sa);
    k_score<<<4, 576, 0, stream>>>(mpix, w_m1, b_m1, w_m2, b_m2, flag);
    k_attn <<<2304, 256, 0, stream>>>(qs, ks, vs, sa, flag, rel_h, rel_w, w_out, b_out, out);
}